// Round 7
// baseline (49.592 us; speedup 1.0000x reference)
//
#include <hip/hip_runtime.h>

// StructNConv2D_d_with_s — fused spatial (3x3) + channel (16x16) normalized conv.
// d,cd: (4,16,256,256) f32; s_prod_roll: (4,16,9,256,256) f32;
// spatial_weight: (16,1,9,1,1); channel_weight: (16,16,1,1).
// Outputs concatenated: d_out then cd_out, each (4,16,256,256) f32.
//
// R7: 4 waves/SIMD. R6's 128-VGPR an/ad[16] accumulator block capped us at
// 2 waves/SIMD. Now: TPB=256 (4 waves/row), wave w spatial-convs channels
// 4w..4w+3 and parks pd/cs in LDS [16][2][256] f32 (32KB, stride-16B
// conflict-free); 1 barrier; wave w channel-mixes only o=4w..4w+3 (acc = 32
// VGPR), reading all 16 c from LDS. 4096 waves = 16/CU = 4/SIMD; LDS
// 33.7KB -> exactly 4 blocks/CU; launch_bounds(256,4) caps VGPR at 128
// (phase-1 live set ~105, no spill expected — verify WRITE_SIZE!).

#define NB 4
#define NC 16
#define NH 256
#define NW 256
#define NK 9
#define HW (NH * NW)
#define TPB 256

static constexpr float kEPS = 1e-20f;

__device__ __forceinline__ float frcp(float x) { return __builtin_amdgcn_rcpf(x); }

__global__ __launch_bounds__(TPB, 4) void structnconv_fused(
    const float* __restrict__ g_d,
    const float* __restrict__ g_cd,
    const float* __restrict__ g_sp,   // s_prod_roll
    const float* __restrict__ g_sw,   // spatial_weight (16*9)
    const float* __restrict__ g_cw,   // channel_weight (16*16)
    float* __restrict__ g_dout,
    float* __restrict__ g_cdout)
{
    __shared__ float lds_sp[NC][2][NW];   // [c][pd/cs][px] 32 KB
    __shared__ float lds_sw[NC * NK];     // 576 B
    __shared__ float lds_cw[NC * NC];     // 1 KB
    __shared__ float lds_part[8];

    const int t  = threadIdx.x;
    const int wv = t >> 6;        // wave 0..3
    const int ln = t & 63;

    // ---- Stage weights + global sums ----
    float s1 = (t < NC * NK) ? g_sw[t] : 0.f;   // 144 < 256
    float s2 = g_cw[t];                         // 256 == NC*NC
    if (t < NC * NK) lds_sw[t] = s1;
    lds_cw[t] = s2;
    #pragma unroll
    for (int off = 32; off > 0; off >>= 1) {
        s1 += __shfl_down(s1, off);
        s2 += __shfl_down(s2, off);
    }
    if (ln == 0) {
        lds_part[wv]     = s1;
        lds_part[4 + wv] = s2;
    }
    __syncthreads();
    const float inv_sw_sum =
        frcp(lds_part[0] + lds_part[1] + lds_part[2] + lds_part[3] + kEPS);
    const float inv_cw_sum =
        frcp(lds_part[4] + lds_part[5] + lds_part[6] + lds_part[7] + kEPS);

    // ---- Block -> one (b,h) row (bijective XCD swizzle); lane -> 4 px ----
    const int bid = (int)blockIdx.x;                 // 0..1023
    const int swz = (bid & 7) * 128 + (bid >> 3);    // XCD n -> contiguous band
    const int b = swz >> 8;
    const int h = swz & (NH - 1);
    const int w0 = ln << 2;
    const int pix = h * NW + w0;

    // ---- Phase 1: spatial conv for this wave's 4 channels -> LDS ----
    #pragma unroll 1
    for (int ci = 0; ci < 4; ++ci) {
        const int c = (wv << 2) + ci;     // wave-uniform
        const float* pdd = g_d  + (size_t)(b * NC + c) * HW + pix;
        const float* pcc = g_cd + (size_t)(b * NC + c) * HW + pix;
        const float* pss = g_sp + ((size_t)(b * NC + c) * NK) * HW + pix;

        // Stencil rows -> registers (static indices after unroll).
        float dr[3][6], cr[3][6];
        #pragma unroll
        for (int r = 0; r < 3; ++r) {
            const int hh = h + r - 1;
            const int roff = (r - 1) * NW;
            if ((unsigned)hh < (unsigned)NH) {
                const float4 md = *(const float4*)(pdd + roff);
                const float4 mc = *(const float4*)(pcc + roff);
                dr[r][1] = md.x; dr[r][2] = md.y; dr[r][3] = md.z; dr[r][4] = md.w;
                cr[r][1] = mc.x; cr[r][2] = mc.y; cr[r][3] = mc.z; cr[r][4] = mc.w;
                dr[r][0] = (w0 > 0)      ? pdd[roff - 1] : 0.f;
                cr[r][0] = (w0 > 0)      ? pcc[roff - 1] : 0.f;
                dr[r][5] = (w0 + 4 < NW) ? pdd[roff + 4] : 0.f;
                cr[r][5] = (w0 + 4 < NW) ? pcc[roff + 4] : 0.f;
            } else {
                #pragma unroll
                for (int j = 0; j < 6; ++j) { dr[r][j] = 0.f; cr[r][j] = 0.f; }
            }
        }

        float4 sp[NK];
        #pragma unroll
        for (int k = 0; k < NK; ++k)
            sp[k] = *(const float4*)(pss + (size_t)k * HW);

        float nom[4] = {0.f, 0.f, 0.f, 0.f};
        float den[4] = {0.f, 0.f, 0.f, 0.f};
        #pragma unroll
        for (int r = 0; r < 3; ++r) {
            #pragma unroll
            for (int dj = 0; dj < 3; ++dj) {
                const int k = r * 3 + dj;
                const float wck = lds_sw[c * NK + k];   // uniform -> broadcast
                const float sv[4] = {sp[k].x, sp[k].y, sp[k].z, sp[k].w};
                #pragma unroll
                for (int p = 0; p < 4; ++p) {
                    const float cdp = cr[r][dj + p] * sv[p];
                    nom[p] = fmaf(cdp * dr[r][dj + p], wck, nom[p]);
                    den[p] = fmaf(cdp, wck, den[p]);
                }
            }
        }

        float4 csv, pdv;
        csv.x = den[0] * inv_sw_sum;  pdv.x = csv.x * (nom[0] * frcp(den[0] + kEPS));
        csv.y = den[1] * inv_sw_sum;  pdv.y = csv.y * (nom[1] * frcp(den[1] + kEPS));
        csv.z = den[2] * inv_sw_sum;  pdv.z = csv.z * (nom[2] * frcp(den[2] + kEPS));
        csv.w = den[3] * inv_sw_sum;  pdv.w = csv.w * (nom[3] * frcp(den[3] + kEPS));
        *(float4*)&lds_sp[c][0][w0] = pdv;
        *(float4*)&lds_sp[c][1][w0] = csv;
    }

    __syncthreads();

    // ---- Phase 2: channel mix, wave w owns o = 4w..4w+3 ----
    const int o_base = wv << 2;
    float4 an[4], ad[4];
    #pragma unroll
    for (int ol = 0; ol < 4; ++ol) {
        an[ol] = make_float4(0.f, 0.f, 0.f, 0.f);
        ad[ol] = make_float4(0.f, 0.f, 0.f, 0.f);
    }
    #pragma unroll
    for (int c = 0; c < NC; ++c) {
        const float4 pdv = *(const float4*)&lds_sp[c][0][w0];
        const float4 csv = *(const float4*)&lds_sp[c][1][w0];
        #pragma unroll
        for (int ol = 0; ol < 4; ++ol) {
            const float wcv = lds_cw[(o_base + ol) * NC + c];  // uniform
            an[ol].x = fmaf(pdv.x, wcv, an[ol].x);
            an[ol].y = fmaf(pdv.y, wcv, an[ol].y);
            an[ol].z = fmaf(pdv.z, wcv, an[ol].z);
            an[ol].w = fmaf(pdv.w, wcv, an[ol].w);
            ad[ol].x = fmaf(csv.x, wcv, ad[ol].x);
            ad[ol].y = fmaf(csv.y, wcv, ad[ol].y);
            ad[ol].z = fmaf(csv.z, wcv, ad[ol].z);
            ad[ol].w = fmaf(csv.w, wcv, ad[ol].w);
        }
    }

    const size_t outb = (size_t)b * NC * HW + pix;
    #pragma unroll
    for (int ol = 0; ol < 4; ++ol) {
        const int o = o_base + ol;
        float4 dv, cv;
        dv.x = an[ol].x * frcp(ad[ol].x + kEPS);
        dv.y = an[ol].y * frcp(ad[ol].y + kEPS);
        dv.z = an[ol].z * frcp(ad[ol].z + kEPS);
        dv.w = an[ol].w * frcp(ad[ol].w + kEPS);
        cv.x = ad[ol].x * inv_cw_sum;     // devalue_conf == 1
        cv.y = ad[ol].y * inv_cw_sum;
        cv.z = ad[ol].z * inv_cw_sum;
        cv.w = ad[ol].w * inv_cw_sum;
        *(float4*)(g_dout  + outb + (size_t)o * HW) = dv;
        *(float4*)(g_cdout + outb + (size_t)o * HW) = cv;
    }
}

extern "C" void kernel_launch(void* const* d_in, const int* in_sizes, int n_in,
                              void* d_out, int out_size, void* d_ws, size_t ws_size,
                              hipStream_t stream) {
    const float* g_d  = (const float*)d_in[0];
    const float* g_cd = (const float*)d_in[1];
    // d_in[2] = s, d_in[3] = cs : unused by the reference computation.
    const float* g_sp = (const float*)d_in[4];
    const float* g_sw = (const float*)d_in[5];
    const float* g_cw = (const float*)d_in[6];

    float* g_dout  = (float*)d_out;
    float* g_cdout = g_dout + (size_t)NB * NC * HW;

    const int blocks = NB * NH;   // 1024 one-row blocks, 4 c-split waves each
    structnconv_fused<<<blocks, TPB, 0, stream>>>(g_d, g_cd, g_sp, g_sw, g_cw,
                                                  g_dout, g_cdout);
}

// Round 8
// 41.086 us; speedup vs baseline: 1.2070x; 1.2070x over previous
//
#include <hip/hip_runtime.h>

// StructNConv2D_d_with_s — fused spatial (3x3) + channel (16x16) normalized conv.
// d,cd: (4,16,256,256) f32; s_prod_roll: (4,16,9,256,256) f32;
// spatial_weight: (16,1,9,1,1); channel_weight: (16,16,1,1).
// Outputs concatenated: d_out then cd_out, each (4,16,256,256) f32.
//
// R8: R7's 4-wave c-split structure, minus the register clamp that sank it.
// R7's __launch_bounds__(256,4) forced VGPR=64 -> spills (+16.7MB scratch
// writes) + serialized loads -> 49.6us. Now: __launch_bounds__(256) only;
// LDS (34.8KB -> 4 blocks/CU) provides the occupancy path; compiler free to
// hold the ~110-reg phase-1 live set. ci-loop unroll 2 keeps two independent
// load blocks in flight. Wave w: spatial conv c=4w..4w+3 -> LDS pd/cs;
// barrier; mix o=4w..4w+3 (32-VGPR acc) reading all 16 c from LDS.

#define NB 4
#define NC 16
#define NH 256
#define NW 256
#define NK 9
#define HW (NH * NW)
#define TPB 256

static constexpr float kEPS = 1e-20f;

__device__ __forceinline__ float frcp(float x) { return __builtin_amdgcn_rcpf(x); }

__global__ __launch_bounds__(TPB) void structnconv_fused(
    const float* __restrict__ g_d,
    const float* __restrict__ g_cd,
    const float* __restrict__ g_sp,   // s_prod_roll
    const float* __restrict__ g_sw,   // spatial_weight (16*9)
    const float* __restrict__ g_cw,   // channel_weight (16*16)
    float* __restrict__ g_dout,
    float* __restrict__ g_cdout)
{
    __shared__ float lds_sp[NC][2][NW];   // [c][pd/cs][px] 32 KB
    __shared__ float lds_sw[NC * NK];     // 576 B
    __shared__ float lds_cw[NC * NC];     // 1 KB
    __shared__ float lds_part[8];

    const int t  = threadIdx.x;
    const int wv = t >> 6;        // wave 0..3
    const int ln = t & 63;

    // ---- Stage weights + global sums ----
    float s1 = (t < NC * NK) ? g_sw[t] : 0.f;   // 144 < 256
    float s2 = g_cw[t];                         // 256 == NC*NC
    if (t < NC * NK) lds_sw[t] = s1;
    lds_cw[t] = s2;
    #pragma unroll
    for (int off = 32; off > 0; off >>= 1) {
        s1 += __shfl_down(s1, off);
        s2 += __shfl_down(s2, off);
    }
    if (ln == 0) {
        lds_part[wv]     = s1;
        lds_part[4 + wv] = s2;
    }
    __syncthreads();
    const float inv_sw_sum =
        frcp(lds_part[0] + lds_part[1] + lds_part[2] + lds_part[3] + kEPS);
    const float inv_cw_sum =
        frcp(lds_part[4] + lds_part[5] + lds_part[6] + lds_part[7] + kEPS);

    // ---- Block -> one (b,h) row (bijective XCD swizzle); lane -> 4 px ----
    const int bid = (int)blockIdx.x;                 // 0..1023
    const int swz = (bid & 7) * 128 + (bid >> 3);    // XCD n -> contiguous band
    const int b = swz >> 8;
    const int h = swz & (NH - 1);
    const int w0 = ln << 2;
    const int pix = h * NW + w0;

    // ---- Phase 1: spatial conv for this wave's 4 channels -> LDS ----
    #pragma unroll 2
    for (int ci = 0; ci < 4; ++ci) {
        const int c = (wv << 2) + ci;     // wave-uniform
        const float* pdd = g_d  + (size_t)(b * NC + c) * HW + pix;
        const float* pcc = g_cd + (size_t)(b * NC + c) * HW + pix;
        const float* pss = g_sp + ((size_t)(b * NC + c) * NK) * HW + pix;

        // Stencil rows -> registers (static indices after unroll).
        float dr[3][6], cr[3][6];
        #pragma unroll
        for (int r = 0; r < 3; ++r) {
            const int hh = h + r - 1;
            const int roff = (r - 1) * NW;
            if ((unsigned)hh < (unsigned)NH) {
                const float4 md = *(const float4*)(pdd + roff);
                const float4 mc = *(const float4*)(pcc + roff);
                dr[r][1] = md.x; dr[r][2] = md.y; dr[r][3] = md.z; dr[r][4] = md.w;
                cr[r][1] = mc.x; cr[r][2] = mc.y; cr[r][3] = mc.z; cr[r][4] = mc.w;
                dr[r][0] = (w0 > 0)      ? pdd[roff - 1] : 0.f;
                cr[r][0] = (w0 > 0)      ? pcc[roff - 1] : 0.f;
                dr[r][5] = (w0 + 4 < NW) ? pdd[roff + 4] : 0.f;
                cr[r][5] = (w0 + 4 < NW) ? pcc[roff + 4] : 0.f;
            } else {
                #pragma unroll
                for (int j = 0; j < 6; ++j) { dr[r][j] = 0.f; cr[r][j] = 0.f; }
            }
        }

        float4 sp[NK];
        #pragma unroll
        for (int k = 0; k < NK; ++k)
            sp[k] = *(const float4*)(pss + (size_t)k * HW);

        float nom[4] = {0.f, 0.f, 0.f, 0.f};
        float den[4] = {0.f, 0.f, 0.f, 0.f};
        #pragma unroll
        for (int r = 0; r < 3; ++r) {
            #pragma unroll
            for (int dj = 0; dj < 3; ++dj) {
                const int k = r * 3 + dj;
                const float wck = lds_sw[c * NK + k];   // uniform -> broadcast
                const float sv[4] = {sp[k].x, sp[k].y, sp[k].z, sp[k].w};
                #pragma unroll
                for (int p = 0; p < 4; ++p) {
                    const float cdp = cr[r][dj + p] * sv[p];
                    nom[p] = fmaf(cdp * dr[r][dj + p], wck, nom[p]);
                    den[p] = fmaf(cdp, wck, den[p]);
                }
            }
        }

        float4 csv, pdv;
        csv.x = den[0] * inv_sw_sum;  pdv.x = csv.x * (nom[0] * frcp(den[0] + kEPS));
        csv.y = den[1] * inv_sw_sum;  pdv.y = csv.y * (nom[1] * frcp(den[1] + kEPS));
        csv.z = den[2] * inv_sw_sum;  pdv.z = csv.z * (nom[2] * frcp(den[2] + kEPS));
        csv.w = den[3] * inv_sw_sum;  pdv.w = csv.w * (nom[3] * frcp(den[3] + kEPS));
        *(float4*)&lds_sp[c][0][w0] = pdv;
        *(float4*)&lds_sp[c][1][w0] = csv;
    }

    __syncthreads();

    // ---- Phase 2: channel mix, wave w owns o = 4w..4w+3 ----
    const int o_base = wv << 2;
    float4 an[4], ad[4];
    #pragma unroll
    for (int ol = 0; ol < 4; ++ol) {
        an[ol] = make_float4(0.f, 0.f, 0.f, 0.f);
        ad[ol] = make_float4(0.f, 0.f, 0.f, 0.f);
    }
    #pragma unroll
    for (int c = 0; c < NC; ++c) {
        const float4 pdv = *(const float4*)&lds_sp[c][0][w0];
        const float4 csv = *(const float4*)&lds_sp[c][1][w0];
        #pragma unroll
        for (int ol = 0; ol < 4; ++ol) {
            const float wcv = lds_cw[(o_base + ol) * NC + c];  // uniform
            an[ol].x = fmaf(pdv.x, wcv, an[ol].x);
            an[ol].y = fmaf(pdv.y, wcv, an[ol].y);
            an[ol].z = fmaf(pdv.z, wcv, an[ol].z);
            an[ol].w = fmaf(pdv.w, wcv, an[ol].w);
            ad[ol].x = fmaf(csv.x, wcv, ad[ol].x);
            ad[ol].y = fmaf(csv.y, wcv, ad[ol].y);
            ad[ol].z = fmaf(csv.z, wcv, ad[ol].z);
            ad[ol].w = fmaf(csv.w, wcv, ad[ol].w);
        }
    }

    const size_t outb = (size_t)b * NC * HW + pix;
    #pragma unroll
    for (int ol = 0; ol < 4; ++ol) {
        const int o = o_base + ol;
        float4 dv, cv;
        dv.x = an[ol].x * frcp(ad[ol].x + kEPS);
        dv.y = an[ol].y * frcp(ad[ol].y + kEPS);
        dv.z = an[ol].z * frcp(ad[ol].z + kEPS);
        dv.w = an[ol].w * frcp(ad[ol].w + kEPS);
        cv.x = ad[ol].x * inv_cw_sum;     // devalue_conf == 1
        cv.y = ad[ol].y * inv_cw_sum;
        cv.z = ad[ol].z * inv_cw_sum;
        cv.w = ad[ol].w * inv_cw_sum;
        *(float4*)(g_dout  + outb + (size_t)o * HW) = dv;
        *(float4*)(g_cdout + outb + (size_t)o * HW) = cv;
    }
}

extern "C" void kernel_launch(void* const* d_in, const int* in_sizes, int n_in,
                              void* d_out, int out_size, void* d_ws, size_t ws_size,
                              hipStream_t stream) {
    const float* g_d  = (const float*)d_in[0];
    const float* g_cd = (const float*)d_in[1];
    // d_in[2] = s, d_in[3] = cs : unused by the reference computation.
    const float* g_sp = (const float*)d_in[4];
    const float* g_sw = (const float*)d_in[5];
    const float* g_cw = (const float*)d_in[6];

    float* g_dout  = (float*)d_out;
    float* g_cdout = g_dout + (size_t)NB * NC * HW;

    const int blocks = NB * NH;   // 1024 one-row blocks, 4 c-split waves each
    structnconv_fused<<<blocks, TPB, 0, stream>>>(g_d, g_cd, g_sp, g_sw, g_cw,
                                                  g_dout, g_cdout);
}